// Round 1
// baseline (288.957 us; speedup 1.0000x reference)
//
#include <hip/hip_runtime.h>

// Problem constants (from reference setup_inputs)
#define B    128
#define H    14
#define W    14
#define C    512
#define NCLS 200
#define HW   (H * W)          // 196
#define TP_DIM 15             // t_p is [15,15,14,14]
#define SENT_OFF ((14 * TP_DIM + 14) * HW)  // sentinel template row offset

// ---------------------------------------------------------------------------
// Kernel 0: cls[b] = argmax(gt[b, :])  (first occurrence on ties)
// ---------------------------------------------------------------------------
__global__ void cls_argmax_kernel(const float* __restrict__ gt,
                                  int* __restrict__ cls) {
    int b = blockIdx.x * blockDim.x + threadIdx.x;
    if (b >= B) return;
    const float* g = gt + (size_t)b * NCLS;
    float best = g[0];
    int bi = 0;
    for (int i = 1; i < NCLS; ++i) {
        float v = g[i];
        if (v > best) { best = v; bi = i; }  // strict > keeps first occurrence
    }
    cls[b] = bi;
}

// ---------------------------------------------------------------------------
// Kernel 1: per (b, c) spatial argmax over 196 positions.
// Emits the flat element offset of the t_p row to use: (h*15 + w) * 196,
// or the sentinel row if the spatial max is exactly 0.
// Consecutive threads = consecutive channels -> coalesced loads.
// ---------------------------------------------------------------------------
__global__ void spatial_argmax_kernel(const float* __restrict__ x,
                                      int* __restrict__ hwoff) {
    int idx = blockIdx.x * blockDim.x + threadIdx.x;  // over B*C
    if (idx >= B * C) return;
    int b = idx / C;
    int c = idx - b * C;
    const float* xp = x + (size_t)b * HW * C + c;
    float best = xp[0];
    int bi = 0;
    for (int s = 1; s < HW; ++s) {
        float v = xp[(size_t)s * C];
        if (v > best) { best = v; bi = s; }  // strict > = first occurrence
    }
    int off;
    if (best == 0.0f) {
        off = SENT_OFF;
    } else {
        int h = bi / W;
        int w = bi - h * W;
        off = (h * TP_DIM + w) * HW;
    }
    hwoff[idx] = off;
}

// ---------------------------------------------------------------------------
// Kernel 2: elementwise pass.
// Block handles (b, 4 consecutive spatial positions); thread = channel.
//   t      = t_p[row(b,c) + s]                (scattered, but t_p is 176 KB -> L2)
//   masked = relu(x * t) * class_templates[cls[b], s, c]
// Outputs (concatenated flat): [masked | x | templates], each B*HW*C floats.
// ---------------------------------------------------------------------------
#define SPB 4  // spatial positions per block (HW % SPB == 0: 196/4 = 49)

__global__ __launch_bounds__(C) void main_kernel(
        const float* __restrict__ x,
        const float* __restrict__ t_p,
        const float* __restrict__ ctpl,
        const int*   __restrict__ hwoff,
        const int*   __restrict__ cls,
        float*       __restrict__ out) {
    int blk = blockIdx.x;
    int b   = blk / (HW / SPB);
    int s0  = (blk - b * (HW / SPB)) * SPB;
    int c   = threadIdx.x;

    int off     = hwoff[b * C + c];
    int klass   = cls[b];

    const size_t plane = (size_t)B * HW * C;
    const size_t base  = ((size_t)b * HW + s0) * C + c;

    const float* __restrict__ trow = t_p + off;
    const float* __restrict__ xp   = x + base;
    const float* __restrict__ cp   = ctpl + ((size_t)klass * HW + s0) * C + c;
    float* __restrict__ out_m = out + base;
    float* __restrict__ out_x = out + plane + base;
    float* __restrict__ out_t = out + 2 * plane + base;

#pragma unroll
    for (int i = 0; i < SPB; ++i) {
        float t  = trow[s0 + i];
        float xv = xp[(size_t)i * C];
        float ct = cp[(size_t)i * C];
        float m  = fmaxf(xv * t, 0.0f) * ct;  // relu(x*t) * class_template
        out_m[(size_t)i * C] = m;
        out_x[(size_t)i * C] = xv;
        out_t[(size_t)i * C] = t;
    }
}

// ---------------------------------------------------------------------------
extern "C" void kernel_launch(void* const* d_in, const int* in_sizes, int n_in,
                              void* d_out, int out_size, void* d_ws, size_t ws_size,
                              hipStream_t stream) {
    const float* x    = (const float*)d_in[0];  // [B,H,W,C]
    const float* gt   = (const float*)d_in[1];  // [B,NCLS]
    const float* t_p  = (const float*)d_in[2];  // [15,15,H,W]
    const float* ctpl = (const float*)d_in[3];  // [NCLS,H,W,C]
    float* out = (float*)d_out;                 // [3, B,H,W,C] flat

    int* hwoff = (int*)d_ws;            // B*C ints
    int* cls   = hwoff + (size_t)B * C; // B ints

    hipLaunchKernelGGL(cls_argmax_kernel, dim3(1), dim3(128), 0, stream, gt, cls);

    hipLaunchKernelGGL(spatial_argmax_kernel,
                       dim3((B * C + 255) / 256), dim3(256), 0, stream,
                       x, hwoff);

    hipLaunchKernelGGL(main_kernel,
                       dim3(B * (HW / SPB)), dim3(C), 0, stream,
                       x, t_p, ctpl, hwoff, cls, out);
}

// Round 2
// 280.593 us; speedup vs baseline: 1.0298x; 1.0298x over previous
//
#include <hip/hip_runtime.h>

// Problem constants (from reference setup_inputs)
#define B    128
#define H    14
#define W    14
#define C    512
#define NCLS 200
#define HW   (H * W)          // 196
#define TP_DIM 15             // t_p is [15,15,14,14]
#define SENT_OFF ((14 * TP_DIM + 14) * HW)  // sentinel template row offset

typedef float  v4f __attribute__((ext_vector_type(4)));
typedef int    v4i __attribute__((ext_vector_type(4)));

// ---------------------------------------------------------------------------
// Kernel A: per (b, c) spatial argmax over 196 positions -> t_p row offset.
// Also folds the per-batch class argmax (gt) into block 0's first 128 threads.
// Consecutive threads = consecutive channels -> coalesced strided loads.
// ---------------------------------------------------------------------------
__global__ __launch_bounds__(256) void argmax_kernel(
        const float* __restrict__ x,
        const float* __restrict__ gt,
        int* __restrict__ hwoff,
        int* __restrict__ cls) {
    int idx = blockIdx.x * 256 + threadIdx.x;  // over B*C = 65536
    int b = idx >> 9;          // /C
    int c = idx & (C - 1);

    const float* xp = x + (size_t)b * HW * C + c;
    float best = xp[0];
    int bi = 0;
#pragma unroll 14
    for (int s = 1; s < HW; ++s) {
        float v = xp[(size_t)s * C];
        if (v > best) { best = v; bi = s; }  // strict > = first occurrence
    }
    int off;
    if (best == 0.0f) {
        off = SENT_OFF;
    } else {
        int h = bi / W;
        int w = bi - h * W;
        off = (h * TP_DIM + w) * HW;
    }
    hwoff[idx] = off;

    // fold class argmax: first 128 threads of block 0, one batch each
    if (idx < B) {
        const float* g = gt + (size_t)idx * NCLS;
        float gb = g[0];
        int gi = 0;
        for (int i = 1; i < NCLS; ++i) {
            float v = g[i];
            if (v > gb) { gb = v; gi = i; }
        }
        cls[idx] = gi;
    }
}

// ---------------------------------------------------------------------------
// Kernel B: elementwise pass, 4-channel x 4-spatial tile per thread.
// Block = 128 threads -> 512 channels x 4 spatial positions.
// Grid  = B * 49 blocks.
//   t      = t_p[row(b,c)][s0..s0+3]   one aligned 16-B gather per channel
//   masked = relu(x * t) * class_templates[cls[b]]
// Outputs (flat): [masked | x | templates], each B*HW*C floats, streamed
// with nontemporal stores (no reuse; keep L2 for t_p/ctpl).
// ---------------------------------------------------------------------------
__global__ __launch_bounds__(128) void main_kernel(
        const float* __restrict__ x,
        const float* __restrict__ t_p,
        const float* __restrict__ ctpl,
        const int*   __restrict__ hwoff,
        const int*   __restrict__ cls,
        float*       __restrict__ out) {
    int blk = blockIdx.x;
    int b   = blk / 49;
    int s0  = (blk - b * 49) * 4;
    int c0  = threadIdx.x * 4;      // 4 consecutive channels

    // 4 t_p row offsets for this thread's channels (coalesced int4 load)
    v4i off = *(const v4i*)(hwoff + b * C + c0);
    int klass = cls[b];

    // gather t rows: 4 spatial values per channel, one 16-B load each
    v4f t0 = *(const v4f*)(t_p + off.x + s0);
    v4f t1 = *(const v4f*)(t_p + off.y + s0);
    v4f t2 = *(const v4f*)(t_p + off.z + s0);
    v4f t3 = *(const v4f*)(t_p + off.w + s0);
    // transpose to per-spatial vectors over the 4 channels
    v4f tv[4];
    tv[0] = (v4f){t0.x, t1.x, t2.x, t3.x};
    tv[1] = (v4f){t0.y, t1.y, t2.y, t3.y};
    tv[2] = (v4f){t0.z, t1.z, t2.z, t3.z};
    tv[3] = (v4f){t0.w, t1.w, t2.w, t3.w};

    const size_t plane = (size_t)B * HW * C;
    const size_t base  = ((size_t)b * HW + s0) * C + c0;
    const float* __restrict__ xp = x + base;
    const float* __restrict__ cp = ctpl + ((size_t)klass * HW + s0) * C + c0;
    float* __restrict__ out_m = out + base;
    float* __restrict__ out_x = out + plane + base;
    float* __restrict__ out_t = out + 2 * plane + base;

#pragma unroll
    for (int i = 0; i < 4; ++i) {
        v4f xv = *(const v4f*)(xp + (size_t)i * C);
        v4f ct = *(const v4f*)(cp + (size_t)i * C);
        v4f t  = tv[i];
        v4f m;
        m.x = fmaxf(xv.x * t.x, 0.0f) * ct.x;
        m.y = fmaxf(xv.y * t.y, 0.0f) * ct.y;
        m.z = fmaxf(xv.z * t.z, 0.0f) * ct.z;
        m.w = fmaxf(xv.w * t.w, 0.0f) * ct.w;
        __builtin_nontemporal_store(m,  (v4f*)(out_m + (size_t)i * C));
        __builtin_nontemporal_store(xv, (v4f*)(out_x + (size_t)i * C));
        __builtin_nontemporal_store(t,  (v4f*)(out_t + (size_t)i * C));
    }
}

// ---------------------------------------------------------------------------
extern "C" void kernel_launch(void* const* d_in, const int* in_sizes, int n_in,
                              void* d_out, int out_size, void* d_ws, size_t ws_size,
                              hipStream_t stream) {
    const float* x    = (const float*)d_in[0];  // [B,H,W,C]
    const float* gt   = (const float*)d_in[1];  // [B,NCLS]
    const float* t_p  = (const float*)d_in[2];  // [15,15,H,W]
    const float* ctpl = (const float*)d_in[3];  // [NCLS,H,W,C]
    float* out = (float*)d_out;                 // [3, B,H,W,C] flat

    int* hwoff = (int*)d_ws;            // B*C ints
    int* cls   = hwoff + (size_t)B * C; // B ints

    hipLaunchKernelGGL(argmax_kernel,
                       dim3((B * C) / 256), dim3(256), 0, stream,
                       x, gt, hwoff, cls);

    hipLaunchKernelGGL(main_kernel,
                       dim3(B * (HW / 4)), dim3(128), 0, stream,
                       x, t_p, ctpl, hwoff, cls, out);
}

// Round 3
// 277.499 us; speedup vs baseline: 1.0413x; 1.0111x over previous
//
#include <hip/hip_runtime.h>

// Problem constants (from reference setup_inputs)
#define B    128
#define H    14
#define W    14
#define C    512
#define NCLS 200
#define HW   (H * W)          // 196
#define TP_DIM 15             // t_p is [15,15,14,14]
#define SENT_OFF ((14 * TP_DIM + 14) * HW)  // sentinel template row offset

typedef float  v4f __attribute__((ext_vector_type(4)));
typedef int    v4i __attribute__((ext_vector_type(4)));

// ---------------------------------------------------------------------------
// Kernel A: per (b, c) spatial argmax over 196 positions -> t_p row offset.
// 4-way split within each wave: lane = (part p in [0,4)) x (16 channels),
// each part scans 49 spatial positions; two shfl_xor steps combine with the
// first-occurrence tie-break (greater value wins; equal value -> smaller s).
// 16 waves/CU (4x the old occupancy), 1/4 the dependent-chain depth.
// Per-batch class argmax (gt) folded into block 0's first 128 threads.
// ---------------------------------------------------------------------------
__global__ __launch_bounds__(256) void argmax_kernel(
        const float* __restrict__ x,
        const float* __restrict__ gt,
        int* __restrict__ hwoff,
        int* __restrict__ cls) {
    int tid  = threadIdx.x;
    int lane = tid & 63;
    int wave = tid >> 6;          // 0..3
    int p    = lane >> 4;         // spatial part 0..3
    int cl   = lane & 15;         // channel within group of 16

    int ch = blockIdx.x * 64 + wave * 16 + cl;   // flat b*C + c, < B*C
    int b  = ch >> 9;            // /C
    int c  = ch & (C - 1);

    const int s_base = p * 49;   // parts cover [49p, 49p+49); 4*49 == 196
    const float* xp = x + ((size_t)b * HW + s_base) * C + c;

    float best = xp[0];
    int   bs   = s_base;
#pragma unroll 7
    for (int i = 1; i < 49; ++i) {
        float v = xp[(size_t)i * C];
        if (v > best) { best = v; bs = s_base + i; }  // strict > = first occ.
    }
    // combine the 4 parts: xor 16 (p bit0), xor 32 (p bit1)
#pragma unroll
    for (int d = 16; d <= 32; d <<= 1) {
        float ov = __shfl_xor(best, d);
        int   os = __shfl_xor(bs, d);
        if (ov > best || (ov == best && os < bs)) { best = ov; bs = os; }
    }
    if (p == 0) {
        int off;
        if (best == 0.0f) {
            off = SENT_OFF;
        } else {
            int h = bs / W;
            int w = bs - h * W;
            off = (h * TP_DIM + w) * HW;
        }
        hwoff[ch] = off;
    }

    // fold class argmax: block 0, first 128 threads, one batch each
    if (blockIdx.x == 0 && tid < B) {
        const float* g = gt + (size_t)tid * NCLS;
        float gb = g[0];
        int gi = 0;
        for (int i = 1; i < NCLS; ++i) {
            float v = g[i];
            if (v > gb) { gb = v; gi = i; }
        }
        cls[tid] = gi;
    }
}

// ---------------------------------------------------------------------------
// Kernel B: elementwise pass, 4-channel x 4-spatial tile per thread.
// Block = 128 threads -> 512 channels x 4 spatial positions. Grid = B * 49.
//   t      = t_p[row(b,c)][s0..s0+3]   one aligned 16-B gather per channel
//   masked = relu(x * t) * class_templates[cls[b]]
// Outputs (flat): [masked | x | templates], each B*HW*C floats, streamed
// with nontemporal stores (no reuse; keep L2 for t_p/ctpl).
// ---------------------------------------------------------------------------
__global__ __launch_bounds__(128) void main_kernel(
        const float* __restrict__ x,
        const float* __restrict__ t_p,
        const float* __restrict__ ctpl,
        const int*   __restrict__ hwoff,
        const int*   __restrict__ cls,
        float*       __restrict__ out) {
    int blk = blockIdx.x;
    int b   = blk / 49;
    int s0  = (blk - b * 49) * 4;
    int c0  = threadIdx.x * 4;      // 4 consecutive channels

    v4i off = *(const v4i*)(hwoff + b * C + c0);
    int klass = cls[b];

    // gather t rows: 4 spatial values per channel, one 16-B load each
    v4f t0 = *(const v4f*)(t_p + off.x + s0);
    v4f t1 = *(const v4f*)(t_p + off.y + s0);
    v4f t2 = *(const v4f*)(t_p + off.z + s0);
    v4f t3 = *(const v4f*)(t_p + off.w + s0);
    v4f tv[4];
    tv[0] = (v4f){t0.x, t1.x, t2.x, t3.x};
    tv[1] = (v4f){t0.y, t1.y, t2.y, t3.y};
    tv[2] = (v4f){t0.z, t1.z, t2.z, t3.z};
    tv[3] = (v4f){t0.w, t1.w, t2.w, t3.w};

    const size_t plane = (size_t)B * HW * C;
    const size_t base  = ((size_t)b * HW + s0) * C + c0;
    const float* __restrict__ xp = x + base;
    const float* __restrict__ cp = ctpl + ((size_t)klass * HW + s0) * C + c0;
    float* __restrict__ out_m = out + base;
    float* __restrict__ out_x = out + plane + base;
    float* __restrict__ out_t = out + 2 * plane + base;

#pragma unroll
    for (int i = 0; i < 4; ++i) {
        v4f xv = *(const v4f*)(xp + (size_t)i * C);
        v4f ct = *(const v4f*)(cp + (size_t)i * C);
        v4f t  = tv[i];
        v4f m;
        m.x = fmaxf(xv.x * t.x, 0.0f) * ct.x;
        m.y = fmaxf(xv.y * t.y, 0.0f) * ct.y;
        m.z = fmaxf(xv.z * t.z, 0.0f) * ct.z;
        m.w = fmaxf(xv.w * t.w, 0.0f) * ct.w;
        __builtin_nontemporal_store(m,  (v4f*)(out_m + (size_t)i * C));
        __builtin_nontemporal_store(xv, (v4f*)(out_x + (size_t)i * C));
        __builtin_nontemporal_store(t,  (v4f*)(out_t + (size_t)i * C));
    }
}

// ---------------------------------------------------------------------------
extern "C" void kernel_launch(void* const* d_in, const int* in_sizes, int n_in,
                              void* d_out, int out_size, void* d_ws, size_t ws_size,
                              hipStream_t stream) {
    const float* x    = (const float*)d_in[0];  // [B,H,W,C]
    const float* gt   = (const float*)d_in[1];  // [B,NCLS]
    const float* t_p  = (const float*)d_in[2];  // [15,15,H,W]
    const float* ctpl = (const float*)d_in[3];  // [NCLS,H,W,C]
    float* out = (float*)d_out;                 // [3, B,H,W,C] flat

    int* hwoff = (int*)d_ws;            // B*C ints
    int* cls   = hwoff + (size_t)B * C; // B ints

    hipLaunchKernelGGL(argmax_kernel,
                       dim3(B * C / 64), dim3(256), 0, stream,
                       x, gt, hwoff, cls);

    hipLaunchKernelGGL(main_kernel,
                       dim3(B * (HW / 4)), dim3(128), 0, stream,
                       x, t_p, ctpl, hwoff, cls, out);
}

// Round 4
// 266.560 us; speedup vs baseline: 1.0840x; 1.0410x over previous
//
#include <hip/hip_runtime.h>

// Problem constants (from reference setup_inputs)
#define B    128
#define H    14
#define W    14
#define C    512
#define NCLS 200
#define HW   (H * W)          // 196
#define TP_DIM 15             // t_p is [15,15,14,14]
#define SENT_OFF ((14 * TP_DIM + 14) * HW)  // sentinel template row offset

typedef float  v4f __attribute__((ext_vector_type(4)));
typedef int    v4i __attribute__((ext_vector_type(4)));

// ---------------------------------------------------------------------------
// Fully fused kernel. Grid = 256 blocks (2 per batch), 512 threads.
//   Phase 1: thread c computes spatial argmax of x[b, :, c] (196 strided,
//            coalesced loads; strict > = first occurrence) -> t_p row offset
//            into LDS. Wave 0 concurrently reduces argmax(gt[b]) via shfl
//            with index-min tie-break. Both half-blocks of a batch do this
//            redundantly -> zero inter-block dependencies; x slice (401 KB)
//            is L1/L2-hot for phase 2.
//   Phase 2: 4-channel x 4-spatial tiles; this block's spatial half of the
//            batch. t gather = one 16-B L2-resident load per channel.
//            masked = relu(x*t) * class_templates[cls]. Outputs streamed
//            with nontemporal stores ([masked | x | templates] flat).
// ---------------------------------------------------------------------------
__global__ __launch_bounds__(512) void fused_kernel(
        const float* __restrict__ x,
        const float* __restrict__ gt,
        const float* __restrict__ t_p,
        const float* __restrict__ ctpl,
        float*       __restrict__ out) {
    __shared__ int s_off[C];
    __shared__ int s_cls;

    const int tid  = threadIdx.x;
    const int b    = blockIdx.x >> 1;
    const int half = blockIdx.x & 1;

    // ---------------- Phase 1a: spatial argmax for channel tid ------------
    {
        const float* xp = x + (size_t)b * HW * C + tid;
        float best = xp[0];
        int   bs   = 0;
#pragma unroll 13
        for (int s = 1; s < HW; ++s) {
            float v = xp[(size_t)s * C];
            if (v > best) { best = v; bs = s; }  // strict > = first occurrence
        }
        int off;
        if (best == 0.0f) {
            off = SENT_OFF;
        } else {
            int h = bs / W;
            int w = bs - h * W;
            off = (h * TP_DIM + w) * HW;
        }
        s_off[tid] = off;
    }

    // ---------------- Phase 1b: class argmax (wave 0 only) ----------------
    if (tid < 64) {
        const float* g = gt + (size_t)b * NCLS;
        float gb = -__builtin_inff();
        int   gi = NCLS;
        for (int i = tid; i < NCLS; i += 64) {   // ascending per lane
            float v = g[i];
            if (v > gb) { gb = v; gi = i; }      // keeps smallest index
        }
#pragma unroll
        for (int d = 1; d < 64; d <<= 1) {
            float ov = __shfl_xor(gb, d);
            int   oi = __shfl_xor(gi, d);
            if (ov > gb || (ov == gb && oi < gi)) { gb = ov; gi = oi; }
        }
        if (tid == 0) s_cls = gi;
    }

    __syncthreads();

    // ---------------- Phase 2: elementwise streaming ----------------------
    const int klass   = s_cls;
    const int q_base  = half ? 25 : 0;           // spatial quads 0..24 / 25..48
    const int n_quads = half ? 24 : 25;          // 49 quads total (196/4)
    const int n_tiles = n_quads * 128;           // channel-groups of 4

    const size_t plane = (size_t)B * HW * C;

    for (int e = tid; e < n_tiles; e += 512) {
        int cg = e & 127;
        int q  = e >> 7;
        int s0 = (q_base + q) * 4;
        int c0 = cg * 4;

        // 4 t_p row offsets from LDS
        int o0 = s_off[c0 + 0];
        int o1 = s_off[c0 + 1];
        int o2 = s_off[c0 + 2];
        int o3 = s_off[c0 + 3];

        // one aligned 16-B gather per channel (t_p is 176 KB -> L2-resident)
        v4f t0 = *(const v4f*)(t_p + o0 + s0);
        v4f t1 = *(const v4f*)(t_p + o1 + s0);
        v4f t2 = *(const v4f*)(t_p + o2 + s0);
        v4f t3 = *(const v4f*)(t_p + o3 + s0);
        v4f tv[4];
        tv[0] = (v4f){t0.x, t1.x, t2.x, t3.x};
        tv[1] = (v4f){t0.y, t1.y, t2.y, t3.y};
        tv[2] = (v4f){t0.z, t1.z, t2.z, t3.z};
        tv[3] = (v4f){t0.w, t1.w, t2.w, t3.w};

        const size_t base = ((size_t)b * HW + s0) * C + c0;
        const float* __restrict__ xp = x + base;
        const float* __restrict__ cp = ctpl + ((size_t)klass * HW + s0) * C + c0;
        float* __restrict__ out_m = out + base;
        float* __restrict__ out_x = out + plane + base;
        float* __restrict__ out_t = out + 2 * plane + base;

#pragma unroll
        for (int i = 0; i < 4; ++i) {
            v4f xv = *(const v4f*)(xp + (size_t)i * C);
            v4f ct = *(const v4f*)(cp + (size_t)i * C);
            v4f t  = tv[i];
            v4f m;
            m.x = fmaxf(xv.x * t.x, 0.0f) * ct.x;
            m.y = fmaxf(xv.y * t.y, 0.0f) * ct.y;
            m.z = fmaxf(xv.z * t.z, 0.0f) * ct.z;
            m.w = fmaxf(xv.w * t.w, 0.0f) * ct.w;
            __builtin_nontemporal_store(m,  (v4f*)(out_m + (size_t)i * C));
            __builtin_nontemporal_store(xv, (v4f*)(out_x + (size_t)i * C));
            __builtin_nontemporal_store(t,  (v4f*)(out_t + (size_t)i * C));
        }
    }
}

// ---------------------------------------------------------------------------
extern "C" void kernel_launch(void* const* d_in, const int* in_sizes, int n_in,
                              void* d_out, int out_size, void* d_ws, size_t ws_size,
                              hipStream_t stream) {
    const float* x    = (const float*)d_in[0];  // [B,H,W,C]
    const float* gt   = (const float*)d_in[1];  // [B,NCLS]
    const float* t_p  = (const float*)d_in[2];  // [15,15,H,W]
    const float* ctpl = (const float*)d_in[3];  // [NCLS,H,W,C]
    float* out = (float*)d_out;                 // [3, B,H,W,C] flat

    hipLaunchKernelGGL(fused_kernel,
                       dim3(2 * B), dim3(512), 0, stream,
                       x, gt, t_p, ctpl, out);
}